// Round 5
// baseline (481.807 us; speedup 1.0000x reference)
//
#include <hip/hip_runtime.h>
#include <math.h>

// Problem constants (from reference)
#define NN 20000      // nodes
#define EE 640000     // edges
#define HH 2          // heads
#define DD 64         // dim
#define LL 4          // layers
#define HD 128        // H*D

// ---------------- DPP helpers (intra-16-lane reduction, pure VALU) ----------------

__device__ __forceinline__ float dpp_add(float x, float y_as_dpp) { return x + y_as_dpp; }

// sum across each 16-lane row: quad_perm swaps then row rotations
__device__ __forceinline__ float row16_sum(float x) {
    int t;
    t = __builtin_amdgcn_update_dpp(0, __float_as_int(x), 0xB1, 0xF, 0xF, true);  // quad_perm [1,0,3,2]
    x += __int_as_float(t);
    t = __builtin_amdgcn_update_dpp(0, __float_as_int(x), 0x4E, 0xF, 0xF, true);  // quad_perm [2,3,0,1]
    x += __int_as_float(t);
    t = __builtin_amdgcn_update_dpp(0, __float_as_int(x), 0x124, 0xF, 0xF, true); // row_ror:4
    x += __int_as_float(t);
    t = __builtin_amdgcn_update_dpp(0, __float_as_int(x), 0x128, 0xF, 0xF, true); // row_ror:8
    x += __int_as_float(t);
    return x;
}

// exchange with lane^16 (stays within 32-lane half) — single DS op
__device__ __forceinline__ float swz_xor16(float x) {
    return __int_as_float(__builtin_amdgcn_ds_swizzle(__float_as_int(x), 0x401F));
}

// ---------------- CSR build ----------------

__global__ void hist_kernel(const int* __restrict__ dst, int* __restrict__ deg) {
    int e = blockIdx.x * 256 + threadIdx.x;
    if (e < EE) atomicAdd(&deg[dst[e]], 1);
}

// single-block exclusive scan, 1024 threads, wave-shuffle based
__global__ void scan_kernel(const int* __restrict__ deg, int* __restrict__ offsets, int n) {
    __shared__ int wsum[16];
    __shared__ int carry;
    int tid = threadIdx.x, wid = tid >> 6, lane = tid & 63;
    if (tid == 0) carry = 0;
    __syncthreads();
    for (int base = 0; base < n; base += 1024) {
        int i = base + tid;
        int v = (i < n) ? deg[i] : 0;
        int x = v;
#pragma unroll
        for (int off = 1; off < 64; off <<= 1) {
            int t = __shfl_up(x, off);
            if (lane >= off) x += t;
        }
        if (lane == 63) wsum[wid] = x;
        __syncthreads();
        if (wid == 0) {
            int wv = (lane < 16) ? wsum[lane] : 0;
#pragma unroll
            for (int off = 1; off < 16; off <<= 1) {
                int t = __shfl_up(wv, off);
                if (lane >= off) wv += t;
            }
            if (lane < 16) wsum[lane] = wv;   // inclusive wave sums
        }
        __syncthreads();
        int prefix = carry + (wid > 0 ? wsum[wid - 1] : 0);
        if (i < n) offsets[i] = prefix + x - v;   // exclusive
        __syncthreads();
        if (tid == 0) carry += wsum[15];
        __syncthreads();
    }
    if (threadIdx.x == 0) offsets[n] = carry;
}

__global__ void scatter_kernel(const int* __restrict__ src, const int* __restrict__ dst,
                               const int* __restrict__ offsets, int* __restrict__ cursor,
                               int* __restrict__ csr_src) {
    int e = blockIdx.x * 256 + threadIdx.x;
    if (e >= EE) return;
    int d = dst[e];
    int pos = offsets[d] + atomicAdd(&cursor[d], 1);
    csr_src[pos] = src[e];
}

// ---------------- per-layer kernels ----------------

// xl = x@Wl + bl ; xr = x@Wr + br  ([N,64] x [64,128])
__global__ void gemm_lr(const float* __restrict__ x,
                        const float* __restrict__ Wl, const float* __restrict__ bl,
                        const float* __restrict__ Wr, const float* __restrict__ br,
                        float* __restrict__ xl, float* __restrict__ xr) {
    __shared__ float xs[16][DD];
    int row0 = blockIdx.x * 16;
    for (int t = threadIdx.x; t < 16 * DD; t += 128) {
        xs[t >> 6][t & 63] = x[row0 * DD + t];
    }
    __syncthreads();
    int j = threadIdx.x;
    float accl[16], accr[16];
    float blv = bl[j], brv = br[j];
#pragma unroll
    for (int r = 0; r < 16; ++r) { accl[r] = blv; accr[r] = brv; }
    for (int k = 0; k < DD; ++k) {
        float wl = Wl[k * HD + j];
        float wr = Wr[k * HD + j];
#pragma unroll
        for (int r = 0; r < 16; ++r) {
            float xv = xs[r][k];
            accl[r] += xv * wl;
            accr[r] += xv * wr;
        }
    }
#pragma unroll
    for (int r = 0; r < 16; ++r) {
        xl[(row0 + r) * HD + j] = accl[r];
        xr[(row0 + r) * HD + j] = accr[r];
    }
}

// Fused GATv2 edge phase: one wave per node.
// Lane layout: group g = lane>>4; head h = g>>1; edge slot es = g&1;
// each lane holds a float4 feature quarter (fo = (lane&15)*4) of head h.
// Per iteration: 2 edges x 2 heads, 1 dwordx4 gather + 1 dword index load + 1 ds_swizzle;
// intra-16 logit reduction is pure-VALU DPP. Index + row loads software-pipelined
// (depth 2, branchless via clamping) so the gather pipe never drains.
__global__ void fused_aggregate(const float* __restrict__ xl, const float* __restrict__ xr,
                                const float* __restrict__ att, const int* __restrict__ offsets,
                                const int* __restrict__ csr_src, const float* __restrict__ bias,
                                float* __restrict__ xout) {
    int lane = threadIdx.x & 63;
    int node = blockIdx.x * 4 + (threadIdx.x >> 6);
    int g = lane >> 4;
    int h = g >> 1;       // head
    int es = g & 1;       // edge slot within iteration
    int fo = (lane & 15) * 4;
    unsigned loff = h * 64 + fo;    // float offset within a row

    int start = offsets[node];
    int deg = offsets[node + 1] - start;

    const float4 xrv = *(const float4*)&xr[((unsigned)node << 7) + loff];
    const float4 attv = *(const float4*)&att[loff];

    float m = -INFINITY;          // running max  (uniform within head half)
    float ssum = 0.f;             // running denom (uniform within head half)
    float4 acc = {0.f, 0.f, 0.f, 0.f};   // per-slot partial message

    if (deg > 0) {
        int dend = start + deg - 1;   // last valid csr position (clamp target)
        int niter = (deg + 1) >> 1;

        // pipeline prologue: indices for edges (0,1) and (2,3); row for edge es
        int s_cur = csr_src[min(start + es, dend)];
        int s_nxt = csr_src[min(start + 2 + es, dend)];
        float4 xlv = *(const float4*)&xl[((unsigned)s_cur << 7) + loff];

        for (int i = 0; i < niter; ++i) {
            // prefetch: row for iteration i+1, index for iteration i+2 (clamped, branchless)
            float4 nxt = *(const float4*)&xl[((unsigned)s_nxt << 7) + loff];
            int s_nxt2 = csr_src[min(start + 2 * i + 4 + es, dend)];

            // attention partial: att . leaky_relu(xl + xr, 0.2), this lane's quarter
            float4 v;
            v.x = xlv.x + xrv.x; v.y = xlv.y + xrv.y;
            v.z = xlv.z + xrv.z; v.w = xlv.w + xrv.w;
            v.x = fmaxf(v.x, 0.f) + 0.2f * fminf(v.x, 0.f);
            v.y = fmaxf(v.y, 0.f) + 0.2f * fminf(v.y, 0.f);
            v.z = fmaxf(v.z, 0.f) + 0.2f * fminf(v.z, 0.f);
            v.w = fmaxf(v.w, 0.f) + 0.2f * fminf(v.w, 0.f);
            float t = fmaf(v.x, attv.x, fmaf(v.y, attv.y, fmaf(v.z, attv.z, v.w * attv.w)));
            // reduce across the 16-lane group: pure VALU (DPP)
            t = row16_sum(t);

            bool valid = (2 * i + es) < deg;
            float lg = valid ? t : -INFINITY;
            // exchange masked logit with the other edge slot of this head
            float lgO = swz_xor16(lg);

            // online softmax update (uniform across the head's 32 lanes)
            float mn = fmaxf(m, fmaxf(lg, lgO));
            float c  = __expf(m - mn);        // exp(-inf)=0 handles first edge
            float w  = __expf(lg - mn);
            float wO = __expf(lgO - mn);
            ssum = fmaf(ssum, c, w + wO);
            acc.x = fmaf(acc.x, c, w * xlv.x);
            acc.y = fmaf(acc.y, c, w * xlv.y);
            acc.z = fmaf(acc.z, c, w * xlv.z);
            acc.w = fmaf(acc.w, c, w * xlv.w);
            m = mn;

            xlv = nxt;
            s_nxt = s_nxt2;
        }
    }

    // combine the two edge-slot partials of each head
    acc.x += __shfl_xor(acc.x, 16);
    acc.y += __shfl_xor(acc.y, 16);
    acc.z += __shfl_xor(acc.z, 16);
    acc.w += __shfl_xor(acc.w, 16);

    float inv = 1.0f / (ssum + 1e-16f);      // per-head denom (deg==0 -> acc=0)
    float4 r;
    r.x = acc.x * inv; r.y = acc.y * inv; r.z = acc.z * inv; r.w = acc.w * inv;

    // combine heads (lane L <-> L+32 hold same features of head 0 / head 1)
    r.x += __shfl_xor(r.x, 32);
    r.y += __shfl_xor(r.y, 32);
    r.z += __shfl_xor(r.z, 32);
    r.w += __shfl_xor(r.w, 32);

    if (lane < 16) {
        const float4 bv = *(const float4*)&bias[fo];
        float4 o;
        o.x = 0.5f * r.x + bv.x;
        o.y = 0.5f * r.y + bv.y;
        o.z = 0.5f * r.z + bv.z;
        o.w = 0.5f * r.w + bv.w;
        o.x = o.x > 0.f ? o.x : 0.01f * o.x;
        o.y = o.y > 0.f ? o.y : 0.01f * o.y;
        o.z = o.z > 0.f ? o.z : 0.01f * o.z;
        o.w = o.w > 0.f ? o.w : 0.01f * o.w;
        *(float4*)&xout[(long)node * DD + fo] = o;
    }
}

// out = leaky_relu(x @ Wo + bo, 0.01); 16 rows/block, 64 threads
__global__ void final_gemm(const float* __restrict__ x, const float* __restrict__ Wo,
                           const float* __restrict__ bo, float* __restrict__ out) {
    __shared__ float xs[16][DD];
    int row0 = blockIdx.x * 16;
    for (int t = threadIdx.x; t < 16 * DD; t += 64) {
        xs[t >> 6][t & 63] = x[row0 * DD + t];
    }
    __syncthreads();
    int j = threadIdx.x;
    float acc[16];
    float bv = bo[j];
#pragma unroll
    for (int r = 0; r < 16; ++r) acc[r] = bv;
    for (int k = 0; k < DD; ++k) {
        float w = Wo[k * DD + j];
#pragma unroll
        for (int r = 0; r < 16; ++r) acc[r] += xs[r][k] * w;
    }
#pragma unroll
    for (int r = 0; r < 16; ++r) {
        float v = acc[r];
        v = v > 0.f ? v : 0.01f * v;
        out[(row0 + r) * DD + j] = v;
    }
}

extern "C" void kernel_launch(void* const* d_in, const int* in_sizes, int n_in,
                              void* d_out, int out_size, void* d_ws, size_t ws_size,
                              hipStream_t stream) {
    const int* edge_index = (const int*)d_in[0];
    const int* src = edge_index;
    const int* dst = edge_index + EE;
    // d_in[1] = edge_weight, unused
    const float* pert = (const float*)d_in[2];
    const float* Wl = (const float*)d_in[3];
    const float* bl = (const float*)d_in[4];
    const float* Wr = (const float*)d_in[5];
    const float* br = (const float*)d_in[6];
    const float* att = (const float*)d_in[7];
    const float* bias = (const float*)d_in[8];
    const float* Wo = (const float*)d_in[9];
    const float* bo = (const float*)d_in[10];
    float* out = (float*)d_out;

    // workspace carve-up
    char* w = (char*)d_ws;
    float* xl = (float*)w;            w += (size_t)NN * HD * 4;
    float* xr = (float*)w;            w += (size_t)NN * HD * 4;
    float* xb0 = (float*)w;           w += (size_t)NN * DD * 4;
    float* xb1 = (float*)w;           w += (size_t)NN * DD * 4;
    int* deg = (int*)w;               w += (size_t)NN * 4;
    int* offsets = (int*)w;           w += (size_t)(NN + 1) * 4 + 4; // keep alignment
    int* cursor = (int*)w;            w += (size_t)NN * 4;
    int* csr_src = (int*)w;           w += (size_t)EE * 4;

    // CSR build (dst is layer-invariant; built once per launch)
    hipMemsetAsync(deg, 0, (size_t)NN * 4, stream);
    hipMemsetAsync(cursor, 0, (size_t)NN * 4, stream);
    hist_kernel<<<(EE + 255) / 256, 256, 0, stream>>>(dst, deg);
    scan_kernel<<<1, 1024, 0, stream>>>(deg, offsets, NN);
    scatter_kernel<<<(EE + 255) / 256, 256, 0, stream>>>(src, dst, offsets, cursor, csr_src);

    const float* xin = pert;
    float* bufs[2] = {xb0, xb1};
    for (int l = 0; l < LL; ++l) {
        gemm_lr<<<NN / 16, 128, 0, stream>>>(xin, Wl + (size_t)l * DD * HD, bl + (size_t)l * HD,
                                             Wr + (size_t)l * DD * HD, br + (size_t)l * HD, xl, xr);
        fused_aggregate<<<NN / 4, 256, 0, stream>>>(xl, xr, att + (size_t)l * HD, offsets,
                                                    csr_src, bias + (size_t)l * DD, bufs[l & 1]);
        xin = bufs[l & 1];
    }
    final_gemm<<<NN / 16, 64, 0, stream>>>(xin, Wo, bo, out);
}

// Round 6
// 411.138 us; speedup vs baseline: 1.1719x; 1.1719x over previous
//
#include <hip/hip_runtime.h>
#include <math.h>
#include <float.h>

// Problem constants (from reference)
#define NN 20000      // nodes
#define EE 640000     // edges
#define HH 2          // heads
#define DD 64         // dim
#define LL 4          // layers
#define HD 128        // H*D

// ---------------- DPP helper (intra-16-lane sum, pure VALU) ----------------

__device__ __forceinline__ float row16_sum(float x) {
    int t;
    t = __builtin_amdgcn_update_dpp(0, __float_as_int(x), 0xB1, 0xF, 0xF, true);  // quad_perm [1,0,3,2]
    x += __int_as_float(t);
    t = __builtin_amdgcn_update_dpp(0, __float_as_int(x), 0x4E, 0xF, 0xF, true);  // quad_perm [2,3,0,1]
    x += __int_as_float(t);
    t = __builtin_amdgcn_update_dpp(0, __float_as_int(x), 0x124, 0xF, 0xF, true); // row_ror:4
    x += __int_as_float(t);
    t = __builtin_amdgcn_update_dpp(0, __float_as_int(x), 0x128, 0xF, 0xF, true); // row_ror:8
    x += __int_as_float(t);
    return x;
}

// ---------------- CSR build ----------------

__global__ void hist_kernel(const int* __restrict__ dst, int* __restrict__ deg) {
    int e = blockIdx.x * 256 + threadIdx.x;
    if (e < EE) atomicAdd(&deg[dst[e]], 1);
}

// single-block exclusive scan, 1024 threads, wave-shuffle based
__global__ void scan_kernel(const int* __restrict__ deg, int* __restrict__ offsets, int n) {
    __shared__ int wsum[16];
    __shared__ int carry;
    int tid = threadIdx.x, wid = tid >> 6, lane = tid & 63;
    if (tid == 0) carry = 0;
    __syncthreads();
    for (int base = 0; base < n; base += 1024) {
        int i = base + tid;
        int v = (i < n) ? deg[i] : 0;
        int x = v;
#pragma unroll
        for (int off = 1; off < 64; off <<= 1) {
            int t = __shfl_up(x, off);
            if (lane >= off) x += t;
        }
        if (lane == 63) wsum[wid] = x;
        __syncthreads();
        if (wid == 0) {
            int wv = (lane < 16) ? wsum[lane] : 0;
#pragma unroll
            for (int off = 1; off < 16; off <<= 1) {
                int t = __shfl_up(wv, off);
                if (lane >= off) wv += t;
            }
            if (lane < 16) wsum[lane] = wv;   // inclusive wave sums
        }
        __syncthreads();
        int prefix = carry + (wid > 0 ? wsum[wid - 1] : 0);
        if (i < n) offsets[i] = prefix + x - v;   // exclusive
        __syncthreads();
        if (tid == 0) carry += wsum[15];
        __syncthreads();
    }
    if (threadIdx.x == 0) offsets[n] = carry;
}

__global__ void scatter_kernel(const int* __restrict__ src, const int* __restrict__ dst,
                               const int* __restrict__ offsets, int* __restrict__ cursor,
                               int* __restrict__ csr_src) {
    int e = blockIdx.x * 256 + threadIdx.x;
    if (e >= EE) return;
    int d = dst[e];
    int pos = offsets[d] + atomicAdd(&cursor[d], 1);
    csr_src[pos] = src[e];
}

// ---------------- per-layer kernels ----------------

// xl = x@Wl + bl ; xr = x@Wr + br  ([N,64] x [64,128])
// 8 rows/block, 128 threads (thread j = output column) -> 2500 blocks for latency hiding
__global__ void gemm_lr(const float* __restrict__ x,
                        const float* __restrict__ Wl, const float* __restrict__ bl,
                        const float* __restrict__ Wr, const float* __restrict__ br,
                        float* __restrict__ xl, float* __restrict__ xr) {
    __shared__ float xs[8][DD];
    int row0 = blockIdx.x * 8;
    ((float4*)xs)[threadIdx.x] = ((const float4*)(x + (size_t)row0 * DD))[threadIdx.x];
    __syncthreads();
    int j = threadIdx.x;
    float accl[8], accr[8];
    float blv = bl[j], brv = br[j];
#pragma unroll
    for (int r = 0; r < 8; ++r) { accl[r] = blv; accr[r] = brv; }
    for (int k = 0; k < DD; ++k) {
        float wl = Wl[k * HD + j];
        float wr = Wr[k * HD + j];
#pragma unroll
        for (int r = 0; r < 8; ++r) {
            float xv = xs[r][k];
            accl[r] = fmaf(xv, wl, accl[r]);
            accr[r] = fmaf(xv, wr, accr[r]);
        }
    }
#pragma unroll
    for (int r = 0; r < 8; ++r) {
        xl[(row0 + r) * HD + j] = accl[r];
        xr[(row0 + r) * HD + j] = accr[r];
    }
}

// Fused GATv2 edge phase: one wave per node, 4 edges per iteration.
// Group g = lane>>4 handles edge (4i+g) for BOTH heads; each lane holds a float4
// quarter of head0 (xa) and head1 (xb). Each group keeps a PRIVATE online-softmax
// state (m, ssum, acc per head) -> zero cross-group ops in the loop; the 4 states
// merge once at the epilogue via a 2-round shuffle butterfly with exp rescaling.
// Invalid edge slots use -FLT_MAX logits; pure-invalid groups vanish in the merge.
__global__ void fused_aggregate(const float* __restrict__ xl, const float* __restrict__ xr,
                                const float* __restrict__ att, const int* __restrict__ offsets,
                                const int* __restrict__ csr_src, const float* __restrict__ bias,
                                float* __restrict__ xout) {
    int lane = threadIdx.x & 63;
    int node = blockIdx.x * 4 + (threadIdx.x >> 6);
    int g = lane >> 4;
    int fo = (lane & 15) * 4;

    int start = offsets[node];
    int deg = offsets[node + 1] - start;

    unsigned nrow = (unsigned)node << 7;
    const float4 xra = *(const float4*)&xr[nrow + fo];
    const float4 xrb = *(const float4*)&xr[nrow + 64 + fo];
    const float4 ata = *(const float4*)&att[fo];
    const float4 atb = *(const float4*)&att[64 + fo];

    float ma = -FLT_MAX, mb = -FLT_MAX;   // per-group running max, per head
    float sa = 0.f, sb = 0.f;             // per-group denom
    float4 aa = {0.f, 0.f, 0.f, 0.f};     // per-group weighted message, head 0
    float4 ab = {0.f, 0.f, 0.f, 0.f};     // head 1

    if (deg > 0) {
        int dend = start + deg - 1;       // clamp target for branchless prefetch
        int niter = (deg + 3) >> 2;

        int s_cur = csr_src[min(start + g, dend)];
        int s_nxt = csr_src[min(start + 4 + g, dend)];
        unsigned rc = (unsigned)s_cur << 7;
        float4 xa = *(const float4*)&xl[rc + fo];
        float4 xb = *(const float4*)&xl[rc + 64 + fo];

        for (int i = 0; i < niter; ++i) {
            // prefetch rows for iter i+1 and index for iter i+2 (clamped, branchless)
            unsigned rn = (unsigned)s_nxt << 7;
            float4 na = *(const float4*)&xl[rn + fo];
            float4 nb = *(const float4*)&xl[rn + 64 + fo];
            int s_n2 = csr_src[min(start + 4 * i + 8 + g, dend)];

            // logit partials: att . leaky_relu(xl + xr, 0.2), both heads
            float4 va, vb;
            va.x = xa.x + xra.x; va.y = xa.y + xra.y; va.z = xa.z + xra.z; va.w = xa.w + xra.w;
            vb.x = xb.x + xrb.x; vb.y = xb.y + xrb.y; vb.z = xb.z + xrb.z; vb.w = xb.w + xrb.w;
            va.x = fmaxf(va.x, 0.f) + 0.2f * fminf(va.x, 0.f);
            va.y = fmaxf(va.y, 0.f) + 0.2f * fminf(va.y, 0.f);
            va.z = fmaxf(va.z, 0.f) + 0.2f * fminf(va.z, 0.f);
            va.w = fmaxf(va.w, 0.f) + 0.2f * fminf(va.w, 0.f);
            vb.x = fmaxf(vb.x, 0.f) + 0.2f * fminf(vb.x, 0.f);
            vb.y = fmaxf(vb.y, 0.f) + 0.2f * fminf(vb.y, 0.f);
            vb.z = fmaxf(vb.z, 0.f) + 0.2f * fminf(vb.z, 0.f);
            vb.w = fmaxf(vb.w, 0.f) + 0.2f * fminf(vb.w, 0.f);
            float ta = fmaf(va.x, ata.x, fmaf(va.y, ata.y, fmaf(va.z, ata.z, va.w * ata.w)));
            float tb = fmaf(vb.x, atb.x, fmaf(vb.y, atb.y, fmaf(vb.z, atb.z, vb.w * atb.w)));
            ta = row16_sum(ta);           // pure-VALU intra-group reduction
            tb = row16_sum(tb);

            bool valid = (4 * i + g) < deg;
            float lga = valid ? ta : -FLT_MAX;
            float lgb = valid ? tb : -FLT_MAX;

            // group-local online softmax update, head 0
            float mna = fmaxf(ma, lga);
            float ca = __expf(ma - mna);       // 0 on first valid edge; 1 if unchanged
            float wa = __expf(lga - mna);      // 0 for trailing invalid slots
            sa = fmaf(sa, ca, wa);
            aa.x = fmaf(aa.x, ca, wa * xa.x);
            aa.y = fmaf(aa.y, ca, wa * xa.y);
            aa.z = fmaf(aa.z, ca, wa * xa.z);
            aa.w = fmaf(aa.w, ca, wa * xa.w);
            ma = mna;
            // head 1
            float mnb = fmaxf(mb, lgb);
            float cb = __expf(mb - mnb);
            float wb = __expf(lgb - mnb);
            sb = fmaf(sb, cb, wb);
            ab.x = fmaf(ab.x, cb, wb * xb.x);
            ab.y = fmaf(ab.y, cb, wb * xb.y);
            ab.z = fmaf(ab.z, cb, wb * xb.z);
            ab.w = fmaf(ab.w, cb, wb * xb.w);
            mb = mnb;

            xa = na; xb = nb;
            s_nxt = s_n2;
        }
    }

    // merge the 4 group states: butterfly xor-16 then xor-32, rescale by exp(m-mn).
    // Pure-invalid groups (m == -FLT_MAX) contribute exp(-huge)=0 once merged with
    // any finite-m partner; if both partners are -FLT_MAX, c0=c1=1 and their
    // (bounded) garbage is annihilated in the next round / by ssum ~ 0 at deg==0.
#pragma unroll
    for (int off = 16; off <= 32; off <<= 1) {
        float mo = __shfl_xor(ma, off);
        float so = __shfl_xor(sa, off);
        float4 ao;
        ao.x = __shfl_xor(aa.x, off); ao.y = __shfl_xor(aa.y, off);
        ao.z = __shfl_xor(aa.z, off); ao.w = __shfl_xor(aa.w, off);
        float mn = fmaxf(ma, mo);
        float c0 = __expf(ma - mn), c1 = __expf(mo - mn);
        sa = fmaf(sa, c0, so * c1);
        aa.x = fmaf(aa.x, c0, ao.x * c1);
        aa.y = fmaf(aa.y, c0, ao.y * c1);
        aa.z = fmaf(aa.z, c0, ao.z * c1);
        aa.w = fmaf(aa.w, c0, ao.w * c1);
        ma = mn;

        mo = __shfl_xor(mb, off);
        so = __shfl_xor(sb, off);
        ao.x = __shfl_xor(ab.x, off); ao.y = __shfl_xor(ab.y, off);
        ao.z = __shfl_xor(ab.z, off); ao.w = __shfl_xor(ab.w, off);
        mn = fmaxf(mb, mo);
        c0 = __expf(mb - mn); c1 = __expf(mo - mn);
        sb = fmaf(sb, c0, so * c1);
        ab.x = fmaf(ab.x, c0, ao.x * c1);
        ab.y = fmaf(ab.y, c0, ao.y * c1);
        ab.z = fmaf(ab.z, c0, ao.z * c1);
        ab.w = fmaf(ab.w, c0, ao.w * c1);
        mb = mn;
    }

    float inva = 1.0f / (sa + 1e-16f);    // deg==0 -> acc=0 -> r=0
    float invb = 1.0f / (sb + 1e-16f);

    if (lane < 16) {
        const float4 bv = *(const float4*)&bias[fo];
        float4 o;
        o.x = fmaf(0.5f, fmaf(aa.x, inva, ab.x * invb), bv.x);
        o.y = fmaf(0.5f, fmaf(aa.y, inva, ab.y * invb), bv.y);
        o.z = fmaf(0.5f, fmaf(aa.z, inva, ab.z * invb), bv.z);
        o.w = fmaf(0.5f, fmaf(aa.w, inva, ab.w * invb), bv.w);
        o.x = o.x > 0.f ? o.x : 0.01f * o.x;
        o.y = o.y > 0.f ? o.y : 0.01f * o.y;
        o.z = o.z > 0.f ? o.z : 0.01f * o.z;
        o.w = o.w > 0.f ? o.w : 0.01f * o.w;
        *(float4*)&xout[(size_t)node * DD + fo] = o;
    }
}

// out = leaky_relu(x @ Wo + bo, 0.01); 8 rows/block, 64 threads -> 2500 blocks
__global__ void final_gemm(const float* __restrict__ x, const float* __restrict__ Wo,
                           const float* __restrict__ bo, float* __restrict__ out) {
    __shared__ float xs[8][DD];
    int row0 = blockIdx.x * 8;
    const float4* src4 = (const float4*)(x + (size_t)row0 * DD);
    ((float4*)xs)[threadIdx.x] = src4[threadIdx.x];
    ((float4*)xs)[threadIdx.x + 64] = src4[threadIdx.x + 64];
    __syncthreads();
    int j = threadIdx.x;
    float acc[8];
    float bv = bo[j];
#pragma unroll
    for (int r = 0; r < 8; ++r) acc[r] = bv;
    for (int k = 0; k < DD; ++k) {
        float w = Wo[k * DD + j];
#pragma unroll
        for (int r = 0; r < 8; ++r) acc[r] = fmaf(xs[r][k], w, acc[r]);
    }
#pragma unroll
    for (int r = 0; r < 8; ++r) {
        float v = acc[r];
        v = v > 0.f ? v : 0.01f * v;
        out[(row0 + r) * DD + j] = v;
    }
}

extern "C" void kernel_launch(void* const* d_in, const int* in_sizes, int n_in,
                              void* d_out, int out_size, void* d_ws, size_t ws_size,
                              hipStream_t stream) {
    const int* edge_index = (const int*)d_in[0];
    const int* src = edge_index;
    const int* dst = edge_index + EE;
    // d_in[1] = edge_weight, unused
    const float* pert = (const float*)d_in[2];
    const float* Wl = (const float*)d_in[3];
    const float* bl = (const float*)d_in[4];
    const float* Wr = (const float*)d_in[5];
    const float* br = (const float*)d_in[6];
    const float* att = (const float*)d_in[7];
    const float* bias = (const float*)d_in[8];
    const float* Wo = (const float*)d_in[9];
    const float* bo = (const float*)d_in[10];
    float* out = (float*)d_out;

    // workspace carve-up
    char* w = (char*)d_ws;
    float* xl = (float*)w;            w += (size_t)NN * HD * 4;
    float* xr = (float*)w;            w += (size_t)NN * HD * 4;
    float* xb0 = (float*)w;           w += (size_t)NN * DD * 4;
    float* xb1 = (float*)w;           w += (size_t)NN * DD * 4;
    int* deg = (int*)w;               w += (size_t)NN * 4;
    int* offsets = (int*)w;           w += (size_t)(NN + 1) * 4 + 4; // keep alignment
    int* cursor = (int*)w;            w += (size_t)NN * 4;
    int* csr_src = (int*)w;           w += (size_t)EE * 4;

    // CSR build (dst is layer-invariant; built once per launch)
    hipMemsetAsync(deg, 0, (size_t)NN * 4, stream);
    hipMemsetAsync(cursor, 0, (size_t)NN * 4, stream);
    hist_kernel<<<(EE + 255) / 256, 256, 0, stream>>>(dst, deg);
    scan_kernel<<<1, 1024, 0, stream>>>(deg, offsets, NN);
    scatter_kernel<<<(EE + 255) / 256, 256, 0, stream>>>(src, dst, offsets, cursor, csr_src);

    const float* xin = pert;
    float* bufs[2] = {xb0, xb1};
    for (int l = 0; l < LL; ++l) {
        gemm_lr<<<NN / 8, 128, 0, stream>>>(xin, Wl + (size_t)l * DD * HD, bl + (size_t)l * HD,
                                            Wr + (size_t)l * DD * HD, br + (size_t)l * HD, xl, xr);
        fused_aggregate<<<NN / 4, 256, 0, stream>>>(xl, xr, att + (size_t)l * HD, offsets,
                                                    csr_src, bias + (size_t)l * DD, bufs[l & 1]);
        xin = bufs[l & 1];
    }
    final_gemm<<<NN / 8, 64, 0, stream>>>(xin, Wo, bo, out);
}